// Round 1
// baseline (1082.109 us; speedup 1.0000x reference)
//
#include <hip/hip_runtime.h>
#include <cstdint>

typedef unsigned long long u64;
typedef unsigned int u32;

// ---------------------------------------------------------------------------
// SNN: 64-step scan over 3 spike-gated linear layers.
//   layer0 (input): m += img; fire; m -= fire (no decay)
//   layerK: m += spikes_in @ W; fire; m = fire ? m-1 : m*0.5
//   lin1 uses s0[t]; lin2 uses s1[t-1]; lin3 uses s2[t-1]
// All internal math in f64 to sit at "true" values (spikes are exact 0/1,
// f32->f64 weight conversion exact, decay/subtract exact in f64).
// ---------------------------------------------------------------------------

__global__ __launch_bounds__(256) void k_input(const float* __restrict__ img,
                                               float* __restrict__ out0, // 65 x n
                                               u64* __restrict__ mask0, int n)
{
    int i = blockIdx.x * 256 + threadIdx.x;
    if (i >= n) return;
    double m = 0.0;
    double x = (double)img[i];
    u64 bits = 0;
#pragma unroll
    for (int t = 0; t < 64; ++t) {
        m += x;
        bool fire = (m >= 1.0);
        if (fire) m -= 1.0;          // input layer: no decay
        bits |= (u64)(fire ? 1 : 0) << t;
        out0[(size_t)t * n + i] = fire ? 1.0f : 0.0f;
    }
    out0[(size_t)64 * n + i] = 0.0f; // pad_tail: last row zero
    mask0[i] = bits;
}

// Spike-gated GEMM partials: P[(c*2+h)][tl=0..31][j] = sum over i in chunk c of
// W[i][j] where spike bit (h*32+tl) of mask[i] is set.
// Block = 512 threads: 256 columns x 2 timestep-halves (wave-uniform h).
__global__ __launch_bounds__(512) void k_gemm(const float* __restrict__ W,
                                              const u32* __restrict__ mask32, // 2 words per i
                                              double* __restrict__ P,
                                              int n_in, int n_out, int i_per_chunk)
{
    int j = blockIdx.x * 256 + (threadIdx.x & 255);
    int h = threadIdx.x >> 8;                 // 0/1 timestep half (wave-uniform)
    int c = blockIdx.y;
    int i0 = c * i_per_chunk;
    int i1 = i0 + i_per_chunk;
    if (i1 > n_in) i1 = n_in;

    double acc[32];
#pragma unroll
    for (int t = 0; t < 32; ++t) acc[t] = 0.0;

    for (int i = i0; i < i1; ++i) {
        u32 mh = mask32[2 * i + h];           // wave-uniform -> scalar load
        if (mh == 0u) continue;               // uniform skip
        double wd = (double)W[(size_t)i * n_out + j];  // coalesced
#pragma unroll
        for (int t = 0; t < 32; ++t) {
            // sel = bit ? 1.0 : 0.0 built with uniform SALU ops; one v_fma_f64
            u64 selb = (0ull - (u64)((mh >> t) & 1u)) & 0x3FF0000000000000ull;
            double sel = __builtin_bit_cast(double, selb);
            acc[t] = fma(sel, wd, acc[t]);
        }
    }

    double* p = P + ((size_t)(c * 2 + h) * 32) * n_out + j;
#pragma unroll
    for (int t = 0; t < 32; ++t) p[(size_t)t * n_out] = acc[t];
}

// U[t][j] = sum over chunks c of P[(c*2 + t/32)][t%32][j]  (fixed order: deterministic)
__global__ __launch_bounds__(256) void k_reduceU(const double* __restrict__ P,
                                                 double* __restrict__ U,
                                                 int nchunks, int n_out)
{
    int gid = blockIdx.x * 256 + threadIdx.x;
    int total = 64 * n_out;
    if (gid >= total) return;
    int t = gid / n_out;
    int j = gid - t * n_out;
    int h = t >> 5, tl = t & 31;
    double s = 0.0;
    for (int c = 0; c < nchunks; ++c)
        s += P[((size_t)(c * 2 + h) * 32 + tl) * n_out + j];
    U[gid] = s;
}

// Per-neuron membrane scan. shift=1 => layer consumes previous step's spikes.
__global__ __launch_bounds__(256) void k_scan(const double* __restrict__ U,
                                              float* __restrict__ outS, // 65 x n_out (pad_head)
                                              u64* __restrict__ maskO,  // may be null
                                              int n_out, int shift)
{
    int j = blockIdx.x * 256 + threadIdx.x;
    if (j >= n_out) return;
    double m = 0.0;
    u64 bits = 0;
    outS[j] = 0.0f;                           // row 0 zero (pad_head)
    for (int t = 0; t < 64; ++t) {
        int s = t - shift;
        double u = (s >= 0) ? U[(size_t)s * n_out + j] : 0.0;
        m += u;
        bool fire = (m >= 1.0);
        m = fire ? (m - 1.0) : (m * 0.5);
        bits |= (u64)(fire ? 1 : 0) << t;
        outS[(size_t)(t + 1) * n_out + j] = fire ? 1.0f : 0.0f;
    }
    if (maskO) maskO[j] = bits;
}

extern "C" void kernel_launch(void* const* d_in, const int* in_sizes, int n_in_cnt,
                              void* d_out, int out_size, void* d_ws, size_t ws_size,
                              hipStream_t stream)
{
    const float* img = (const float*)d_in[0];
    const float* w1  = (const float*)d_in[1];
    const float* w2  = (const float*)d_in[2];
    const float* w3  = (const float*)d_in[3];

    const int N0 = 16384, N1 = 4096, N2 = 4096, N3 = 1024;

    float* out0 = (float*)d_out;
    float* out1 = out0 + (size_t)65 * N0;
    float* out2 = out1 + (size_t)65 * N1;
    float* out3 = out2 + (size_t)65 * N2;

    // workspace layout
    char* ws = (char*)d_ws;
    u64*    mask0 = (u64*)(ws);                      // 131072 B
    u64*    mask1 = (u64*)(ws + 131072);             //  32768 B
    u64*    mask2 = (u64*)(ws + 163840);             //  32768 B
    double* U     = (double*)(ws + 196608);          // 64*4096*8 = 2 MiB
    double* P     = (double*)(ws + 196608 + 2097152);

    size_t fixed = 196608 + 2097152;
    size_t pbudget = (ws_size > fixed) ? (ws_size - fixed) : 0;

    // bytes per chunk-pair (2 halves x 32 t x n_out x 8B) = 512*n_out
    auto clampi = [](long v, int lo, int hi) { int x = (int)v; if (x < lo) x = lo; if (x > hi) x = hi; return x; };
    int C1 = clampi((long)(pbudget / (512ull * N1)), 1, 32);
    int C2 = clampi((long)(pbudget / (512ull * N2)), 1, 16);
    int C3 = clampi((long)(pbudget / (512ull * N3)), 1, 16);

    // layer 0 (input)
    k_input<<<N0 / 256, 256, 0, stream>>>(img, out0, mask0, N0);

    // layer 1: U1 = S0 @ W1 (same-step spikes)
    k_gemm<<<dim3(N1 / 256, C1), 512, 0, stream>>>(w1, (const u32*)mask0, P, N0, N1, (N0 + C1 - 1) / C1);
    k_reduceU<<<(64 * N1) / 256, 256, 0, stream>>>(P, U, C1, N1);
    k_scan<<<N1 / 256, 256, 0, stream>>>(U, out1, mask1, N1, 0);

    // layer 2: uses previous-step s1
    k_gemm<<<dim3(N2 / 256, C2), 512, 0, stream>>>(w2, (const u32*)mask1, P, N1, N2, (N1 + C2 - 1) / C2);
    k_reduceU<<<(64 * N2) / 256, 256, 0, stream>>>(P, U, C2, N2);
    k_scan<<<N2 / 256, 256, 0, stream>>>(U, out2, mask2, N2, 1);

    // layer 3: uses previous-step s2
    k_gemm<<<dim3(N3 / 256, C3), 512, 0, stream>>>(w3, (const u32*)mask2, P, N1, N3, (N1 + C3 - 1) / C3);
    k_reduceU<<<(64 * N3) / 256, 256, 0, stream>>>(P, U, C3, N3);
    k_scan<<<N3 / 256, 256, 0, stream>>>(U, out3, (u64*)nullptr, N3, 1);
}

// Round 2
// 617.043 us; speedup vs baseline: 1.7537x; 1.7537x over previous
//
#include <hip/hip_runtime.h>
#include <cstdint>

typedef unsigned long long u64;
typedef unsigned int u32;

// ---------------------------------------------------------------------------
// SNN: 64-step scan over 3 spike-gated linear layers.
//   layer0 (input): m += img; fire; m -= fire (no decay)
//   layerK: m += spikes_in @ W; fire; m = fire ? m-1 : m*0.5
//   lin1 uses s0[t]; lin2 uses s1[t-1]; lin3 uses s2[t-1]
// All internal math in f64 (spikes exact 0/1, f32->f64 exact, decay exact).
// GEMM inner loop: scalar mask word (s_load), scalar select (s_cselect_b64),
// one v_fma_f64 per timestep — VALU floor is 4 cyc per (i, 64j, t).
// ---------------------------------------------------------------------------

__global__ __launch_bounds__(256) void k_input(const float* __restrict__ img,
                                               float* __restrict__ out0, // 65 x n
                                               u64* __restrict__ mask0, int n)
{
    int i = blockIdx.x * 256 + threadIdx.x;
    if (i >= n) return;
    double m = 0.0;
    double x = (double)img[i];
    u64 bits = 0;
#pragma unroll
    for (int t = 0; t < 64; ++t) {
        m += x;
        bool fire = (m >= 1.0);
        if (fire) m -= 1.0;          // input layer: no decay
        bits |= (u64)(fire ? 1 : 0) << t;
        out0[(size_t)t * n + i] = fire ? 1.0f : 0.0f;
    }
    out0[(size_t)64 * n + i] = 0.0f; // pad_tail: last row zero
    mask0[i] = bits;
}

// Spike-gated GEMM partials.
// Grid: (n_out/256, nchunks, 2). Block: 256 threads (one j per thread).
// h = blockIdx.z selects the 32-timestep half -> mask word is wave-uniform
// (scalar load + scalar select; only the f64 FMA hits the vector pipe).
__global__ __launch_bounds__(256) void k_gemm(const float* __restrict__ W,
                                              const u32* __restrict__ mask32, // 2 words per i
                                              double* __restrict__ P,
                                              int n_in, int n_out, int i_per_chunk)
{
    int j = blockIdx.x * 256 + threadIdx.x;
    int h = blockIdx.z;                       // 0/1 timestep half (uniform)
    int c = blockIdx.y;
    int i0 = c * i_per_chunk;
    int i1 = i0 + i_per_chunk;
    if (i1 > n_in) i1 = n_in;

    double acc[32];
#pragma unroll
    for (int t = 0; t < 32; ++t) acc[t] = 0.0;

    const float* wp = W + (size_t)i0 * n_out + j;
    for (int i = i0; i < i1; ++i, wp += n_out) {
        u32 mh = mask32[2 * i + h];           // uniform address -> s_load
        double wd = (double)*wp;              // coalesced vector load + cvt
#pragma unroll
        for (int t = 0; t < 32; ++t) {
            // scalar: s_and_b32 (sets SCC) + s_cselect_b64 {1.0, 0.0};
            // vector: single v_fma_f64 with SGPR-pair multiplicand.
            double sel = (mh & (1u << t)) ? 1.0 : 0.0;
            acc[t] = fma(sel, wd, acc[t]);
        }
    }

    double* p = P + ((size_t)(c * 2 + h) * 32) * n_out + j;
#pragma unroll
    for (int t = 0; t < 32; ++t) p[(size_t)t * n_out] = acc[t];
}

// U[t][j] = sum over chunks c of P[(c*2 + t/32)][t%32][j]  (fixed order: deterministic)
__global__ __launch_bounds__(256) void k_reduceU(const double* __restrict__ P,
                                                 double* __restrict__ U,
                                                 int nchunks, int n_out)
{
    int gid = blockIdx.x * 256 + threadIdx.x;
    int total = 64 * n_out;
    if (gid >= total) return;
    int t = gid / n_out;
    int j = gid - t * n_out;
    int h = t >> 5, tl = t & 31;
    double s = 0.0;
    for (int c = 0; c < nchunks; ++c)
        s += P[((size_t)(c * 2 + h) * 32 + tl) * n_out + j];
    U[gid] = s;
}

// Per-neuron membrane scan. shift=1 => layer consumes previous step's spikes.
__global__ __launch_bounds__(256) void k_scan(const double* __restrict__ U,
                                              float* __restrict__ outS, // 65 x n_out (pad_head)
                                              u64* __restrict__ maskO,  // may be null
                                              int n_out, int shift)
{
    int j = blockIdx.x * 256 + threadIdx.x;
    if (j >= n_out) return;
    double m = 0.0;
    u64 bits = 0;
    outS[j] = 0.0f;                           // row 0 zero (pad_head)
    for (int t = 0; t < 64; ++t) {
        int s = t - shift;
        double u = (s >= 0) ? U[(size_t)s * n_out + j] : 0.0;
        m += u;
        bool fire = (m >= 1.0);
        m = fire ? (m - 1.0) : (m * 0.5);
        bits |= (u64)(fire ? 1 : 0) << t;
        outS[(size_t)(t + 1) * n_out + j] = fire ? 1.0f : 0.0f;
    }
    if (maskO) maskO[j] = bits;
}

extern "C" void kernel_launch(void* const* d_in, const int* in_sizes, int n_in_cnt,
                              void* d_out, int out_size, void* d_ws, size_t ws_size,
                              hipStream_t stream)
{
    const float* img = (const float*)d_in[0];
    const float* w1  = (const float*)d_in[1];
    const float* w2  = (const float*)d_in[2];
    const float* w3  = (const float*)d_in[3];

    const int N0 = 16384, N1 = 4096, N2 = 4096, N3 = 1024;

    float* out0 = (float*)d_out;
    float* out1 = out0 + (size_t)65 * N0;
    float* out2 = out1 + (size_t)65 * N1;
    float* out3 = out2 + (size_t)65 * N2;

    // workspace layout
    char* ws = (char*)d_ws;
    u64*    mask0 = (u64*)(ws);                      // 131072 B
    u64*    mask1 = (u64*)(ws + 131072);             //  32768 B
    u64*    mask2 = (u64*)(ws + 163840);             //  32768 B
    double* U     = (double*)(ws + 196608);          // 64*4096*8 = 2 MiB
    double* P     = (double*)(ws + 196608 + 2097152);

    size_t fixed = 196608 + 2097152;
    size_t pbudget = (ws_size > fixed) ? (ws_size - fixed) : 0;

    // bytes per chunk (2 halves x 32 t x n_out x 8B) = 512*n_out
    auto clampi = [](long v, int lo, int hi) { int x = (int)v; if (x < lo) x = lo; if (x > hi) x = hi; return x; };
    int C1 = clampi((long)(pbudget / (512ull * N1)), 1, 48);
    int C2 = clampi((long)(pbudget / (512ull * N2)), 1, 32);
    int C3 = clampi((long)(pbudget / (512ull * N3)), 1, 64);

    // layer 0 (input)
    k_input<<<N0 / 256, 256, 0, stream>>>(img, out0, mask0, N0);

    // layer 1: U1 = S0 @ W1 (same-step spikes)
    k_gemm<<<dim3(N1 / 256, C1, 2), 256, 0, stream>>>(w1, (const u32*)mask0, P, N0, N1, (N0 + C1 - 1) / C1);
    k_reduceU<<<(64 * N1) / 256, 256, 0, stream>>>(P, U, C1, N1);
    k_scan<<<N1 / 256, 256, 0, stream>>>(U, out1, mask1, N1, 0);

    // layer 2: uses previous-step s1
    k_gemm<<<dim3(N2 / 256, C2, 2), 256, 0, stream>>>(w2, (const u32*)mask1, P, N1, N2, (N1 + C2 - 1) / C2);
    k_reduceU<<<(64 * N2) / 256, 256, 0, stream>>>(P, U, C2, N2);
    k_scan<<<N2 / 256, 256, 0, stream>>>(U, out2, mask2, N2, 1);

    // layer 3: uses previous-step s2
    k_gemm<<<dim3(N3 / 256, C3, 2), 256, 0, stream>>>(w3, (const u32*)mask2, P, N1, N3, (N1 + C3 - 1) / C3);
    k_reduceU<<<(64 * N3) / 256, 256, 0, stream>>>(P, U, C3, N3);
    k_scan<<<N3 / 256, 256, 0, stream>>>(U, out3, (u64*)nullptr, N3, 1);
}